// Round 9
// baseline (384.669 us; speedup 1.0000x reference)
//
#include <hip/hip_runtime.h>
#include <hip/hip_bf16.h>

typedef short bf16x8 __attribute__((ext_vector_type(8)));
typedef float f32x4 __attribute__((ext_vector_type(4)));
typedef unsigned short u16;

#define LOG2E 1.44269504088896340736f
#define AS1 __attribute__((address_space(1)))
#define AS3 __attribute__((address_space(3)))

__device__ __forceinline__ u16 f2bf(float f) {
    unsigned u = __float_as_uint(f);
    u += 0x7fffu + ((u >> 16) & 1u);   // round-to-nearest-even
    return (u16)(u >> 16);
}
__device__ __forceinline__ float bf2f(u16 h) {
    return __uint_as_float(((unsigned)h) << 16);
}
// async global->LDS, 16B/lane. LDS dest is WAVE-UNIFORM base; HW adds lane*16.
__device__ __forceinline__ void gload_lds16(const void* g, void* l) {
    __builtin_amdgcn_global_load_lds((const AS1 unsigned int*)g,
                                     (AS3 unsigned int*)l, 16, 0, 0);
}

// ---------------------------------------------------------------------------
// Kernel 0: weight prep. Combined rows: [0,256)=Wv, [256,288)=Wq*log2e, [288,320)=Wk.
// ---------------------------------------------------------------------------
__global__ void k_prep(const float* __restrict__ Wq, const float* __restrict__ bq,
                       const float* __restrict__ Wk, const float* __restrict__ bk,
                       const float* __restrict__ Wv, const float* __restrict__ bv,
                       u16* __restrict__ Whi, u16* __restrict__ Wlo,
                       float* __restrict__ bias) {
    int idx = blockIdx.x * 256 + threadIdx.x;
    if (idx >= 320 * 256) return;
    int row = idx >> 8, c = idx & 255;
    float w, b;
    if (row < 256)      { w = Wv[row * 256 + c];                  b = bv[row]; }
    else if (row < 288) { w = Wq[(row - 256) * 256 + c] * LOG2E;  b = bq[row - 256] * LOG2E; }
    else                { w = Wk[(row - 288) * 256 + c];          b = bk[row - 288]; }
    u16 hi = f2bf(w);
    Whi[idx] = hi;
    Wlo[idx] = f2bf(w - bf2f(hi));
    if (c == 0) bias[row] = b;
}

// ---------------------------------------------------------------------------
// Kernel 1: fused QKV projection (unchanged from round 8).
// ---------------------------------------------------------------------------
#define XPAD 264

__global__ __launch_bounds__(256) void k_proj(
    const float* __restrict__ x, const u16* __restrict__ Whi,
    const u16* __restrict__ Wlo, const float* __restrict__ bias,
    u16* __restrict__ qt, u16* __restrict__ kt, u16* __restrict__ vbf) {
    __shared__ __attribute__((aligned(16))) u16 xh[64 * XPAD];
    __shared__ __attribute__((aligned(16))) u16 xl[64 * XPAD];
    int bid = blockIdx.x;
    int b = bid & 7, nt = bid >> 3;
    int n0 = nt * 64;
    int t = threadIdx.x;
    int lane = t & 63, w = t >> 6;
    int lr = lane & 15, lk = lane >> 4;

    {
        int n = t & 63;
        int cg = t >> 6;
        for (int it = 0; it < 8; ++it) {
            int c8 = (it * 4 + cg) * 8;
            bf16x8 hv, lv;
#pragma unroll
            for (int u = 0; u < 8; ++u) {
                float xv = x[((size_t)(b * 256 + c8 + u)) * 4096 + n0 + n];
                u16 hu = f2bf(xv);
                hv[u] = (short)hu;
                lv[u] = (short)f2bf(xv - bf2f(hu));
            }
            *(bf16x8*)&xh[n * XPAD + c8] = hv;
            *(bf16x8*)&xl[n * XPAD + c8] = lv;
        }
    }
    __syncthreads();

    f32x4 acc[5][4];
#pragma unroll
    for (int i = 0; i < 5; i++)
#pragma unroll
        for (int j = 0; j < 4; j++) acc[i][j] = (f32x4){0.f, 0.f, 0.f, 0.f};

    for (int cs = 0; cs < 8; ++cs) {
        int c0 = cs * 32;
        bf16x8 ah[5], al[5], bh[4], bl[4];
#pragma unroll
        for (int mt = 0; mt < 5; ++mt) {
            int row = (w * 5 + mt) * 16 + lr;
            ah[mt] = *(const bf16x8*)&Whi[row * 256 + c0 + lk * 8];
            al[mt] = *(const bf16x8*)&Wlo[row * 256 + c0 + lk * 8];
        }
#pragma unroll
        for (int ns = 0; ns < 4; ++ns) {
            int np = ns * 16 + lr;
            bh[ns] = *(const bf16x8*)&xh[np * XPAD + c0 + lk * 8];
            bl[ns] = *(const bf16x8*)&xl[np * XPAD + c0 + lk * 8];
        }
#pragma unroll
        for (int mt = 0; mt < 5; ++mt)
#pragma unroll
            for (int ns = 0; ns < 4; ++ns) {
                acc[mt][ns] = __builtin_amdgcn_mfma_f32_16x16x32_bf16(ah[mt], bh[ns], acc[mt][ns], 0, 0, 0);
                acc[mt][ns] = __builtin_amdgcn_mfma_f32_16x16x32_bf16(ah[mt], bl[ns], acc[mt][ns], 0, 0, 0);
                acc[mt][ns] = __builtin_amdgcn_mfma_f32_16x16x32_bf16(al[mt], bh[ns], acc[mt][ns], 0, 0, 0);
            }
    }

#pragma unroll
    for (int mt = 0; mt < 5; ++mt) {
        int tile = w * 5 + mt;
#pragma unroll
        for (int ns = 0; ns < 4; ++ns) {
#pragma unroll
            for (int r = 0; r < 4; ++r) {
                int row = tile * 16 + lk * 4 + r;
                int n = n0 + ns * 16 + lr;
                float val = acc[mt][ns][r] + bias[row];
                if (row < 256) {
                    vbf[((size_t)(b * 256 + row)) * 4096 + n] = f2bf(val);
                } else if (row < 288) {
                    u16 hi = f2bf(val);
                    size_t base = ((size_t)(b * 4096 + n)) * 64 + (row - 256);
                    qt[base] = hi;
                    qt[base + 32] = f2bf(val - bf2f(hi));
                } else {
                    u16 hi = f2bf(val);
                    size_t base = ((size_t)(b * 4096 + n)) * 64 + (row - 288);
                    kt[base] = hi;
                    kt[base + 32] = f2bf(val - bf2f(hi));
                }
            }
        }
    }
}

// ---------------------------------------------------------------------------
// Kernel 1.5: per-batch safety shift (Cauchy-Schwarz bound), unchanged.
// ---------------------------------------------------------------------------
__global__ __launch_bounds__(256) void k_bound(
    const u16* __restrict__ qt, const u16* __restrict__ kt,
    float* __restrict__ Sh) {
    __shared__ float rq[4], rk[4];
    int b = blockIdx.x;
    int t = threadIdx.x;
    int lane = t & 63, w = t >> 6;
    float qm = 0.f, km = 0.f;
    for (int n = t; n < 4096; n += 256) {
        size_t base = ((size_t)(b * 4096 + n)) * 64;
        float sq = 0.f, sk = 0.f;
#pragma unroll
        for (int g = 0; g < 4; ++g) {
            bf16x8 vq = *(const bf16x8*)&qt[base + g * 8];
            bf16x8 vk = *(const bf16x8*)&kt[base + g * 8];
#pragma unroll
            for (int u = 0; u < 8; ++u) {
                float a = bf2f((u16)vq[u]), c = bf2f((u16)vk[u]);
                sq += a * a;
                sk += c * c;
            }
        }
        qm = fmaxf(qm, sq);
        km = fmaxf(km, sk);
    }
#pragma unroll
    for (int d = 1; d < 64; d <<= 1) {
        qm = fmaxf(qm, __shfl_xor(qm, d));
        km = fmaxf(km, __shfl_xor(km, d));
    }
    if (lane == 0) { rq[w] = qm; rk[w] = km; }
    __syncthreads();
    if (t == 0) {
        float a = fmaxf(fmaxf(rq[0], rq[1]), fmaxf(rq[2], rq[3]));
        float c = fmaxf(fmaxf(rk[0], rk[1]), fmaxf(rk[2], rk[3]));
        Sh[b] = fmaxf(0.f, sqrtf(a) * sqrtf(c) - 80.f);
    }
}

// ---------------------------------------------------------------------------
// Kernel 2: LDS-staged attention GEMM, C-SPLIT for occupancy.
// Grid 1024 = 8 b x 64 jt x 2 ch -> 4 blocks/CU (16 waves/CU). Block (b,jt,ch)
// owns j-tile [jt*64,+64) x c-rows [ch*128,+128). Wave w: produces P for
// j-sub w (16 cols, all i of the tile; duplicated across ch — cheap) and PVs
// c-rows [ch*128 + w*32, +32). Same m97 staging structure as round 8:
// global_load_lds (linear dest, inverse-swizzled source), swizzled ds_read,
// double-buffered q/v/P, ONE barrier per 32-i iteration. Per-lane staging
// source pointers hoisted out of the loop. Output f32.
// ---------------------------------------------------------------------------
#define PSTR 40

__global__ __launch_bounds__(256) void k_attn(
    const u16* __restrict__ qt, const u16* __restrict__ kt,
    const u16* __restrict__ vbf, const float* __restrict__ Sh,
    const float* __restrict__ x, const float* __restrict__ gamma,
    float* __restrict__ out) {
    __shared__ __attribute__((aligned(16))) u16 qlds[2][32 * 64];    //  8 KB
    __shared__ __attribute__((aligned(16))) u16 vlds[2][128 * 32];   // 16 KB
    __shared__ __attribute__((aligned(16))) u16 P[2][4][16][PSTR];   // 10 KB
    __shared__ float Ls[4][16];
    int bid = blockIdx.x;
    int b = bid & 7;                 // pins batch -> XCD (L2 locality)
    int rest = bid >> 3;             // [0,128)
    int jt = rest & 63, ch = rest >> 6;
    int t = threadIdx.x;
    int lane = t & 63, w = t >> 6;
    int lr = lane & 15, lk = lane >> 4;
    int j0 = jt * 64;
    int c0 = ch * 128;               // this block's c-range base

    // K fragments for this wave's production j-subtile (js = w), loaded once
    size_t kb = ((size_t)(b * 4096 + j0 + w * 16 + lr)) * 64 + lk * 8;
    bf16x8 khi = *(const bf16x8*)&kt[kb];
    bf16x8 klo = *(const bf16x8*)&kt[kb + 32];
    float shift = Sh[b];

    // ---- hoisted per-lane staging source pointers (i0-invariant parts) ----
    // v: wave-issue I covers rows [I*16, +16); lane l -> row I*16+(l>>3... )
    //    row = I*16 + (l>>2), phys slot l&3, logical s = (l&3)^((l>>3)&3)
    const int vs = (lane & 3) ^ ((lane >> 3) & 3);
    const u16* vsrc0 = vbf + ((size_t)(b * 256 + c0 + (w * 2 + 0) * 16 + (lane >> 2))) * 4096 + vs * 8;
    const u16* vsrc1 = vbf + ((size_t)(b * 256 + c0 + (w * 2 + 1) * 16 + (lane >> 2))) * 4096 + vs * 8;
    // q: wave w covers rows [w*8, +8); lane l -> row w*8+(l>>3), phys l&7,
    //    logical s = (l&7)^((l>>3)&7); source row scales by 64 u16 with i0
    const u16* qsrc = qt + ((size_t)(b * 4096 + w * 8 + (lane >> 3))) * 64
                         + (((lane & 7) ^ ((lane >> 3) & 7))) * 8;

    auto stage = [&](int nb, int i0) {
        gload_lds16(vsrc0 + i0, &vlds[nb][(w * 2 + 0) * 512]);
        gload_lds16(vsrc1 + i0, &vlds[nb][(w * 2 + 1) * 512]);
        gload_lds16(qsrc + (size_t)i0 * 64, &qlds[nb][w * 512]);
    };

    f32x4 acc[2][4];   // [ct][js]: c = c0+w*32+ct*16+lk*4+r , j = j0+js*16+lr
#pragma unroll
    for (int i = 0; i < 2; i++)
#pragma unroll
        for (int j = 0; j < 4; j++) acc[i][j] = (f32x4){0.f, 0.f, 0.f, 0.f};
    float lsum = 0.f;
    const f32x4 zero = {0.f, 0.f, 0.f, 0.f};

    // prologue: stage tile 0, wait for it
    stage(0, 0);
    __syncthreads();   // compiler emits vmcnt(0) drain before barrier

    for (int it = 0; it < 128; ++it) {
        int buf = it & 1;
        // issue next tile's staging NOW; latency hidden under QK/exp below
        stage(buf ^ 1, ((it + 1) & 127) * 32);

        // ---- QK^T from LDS (swizzled q reads): own 16 j x 32 i ----
        bf16x8 qh[2], ql[2];
#pragma unroll
        for (int g = 0; g < 2; ++g) {
            int i = g * 16 + lr;
            int ph = lk ^ (lr & 7);                        // hi phys slot
            qh[g] = *(const bf16x8*)&qlds[buf][i * 64 + ph * 8];
            ql[g] = *(const bf16x8*)&qlds[buf][i * 64 + (ph ^ 4) * 8];
        }
        f32x4 s[2];
#pragma unroll
        for (int g = 0; g < 2; ++g) {
            s[g] = __builtin_amdgcn_mfma_f32_16x16x32_bf16(qh[g], khi, zero, 0, 0, 0);
            s[g] = __builtin_amdgcn_mfma_f32_16x16x32_bf16(qh[g], klo, s[g], 0, 0, 0);
            s[g] = __builtin_amdgcn_mfma_f32_16x16x32_bf16(ql[g], khi, s[g], 0, 0, 0);
        }

        // ---- P = exp2(s - shift); inline L; pack bf16; write P[buf] ----
#pragma unroll
        for (int g = 0; g < 2; ++g) {
            float p0 = exp2f(s[g][0] - shift), p1 = exp2f(s[g][1] - shift);
            float p2 = exp2f(s[g][2] - shift), p3 = exp2f(s[g][3] - shift);
            lsum += (p0 + p1) + (p2 + p3);
            uint2 pk;
            pk.x = ((unsigned)f2bf(p1) << 16) | f2bf(p0);
            pk.y = ((unsigned)f2bf(p3) << 16) | f2bf(p2);
            *(uint2*)&P[buf][w][lr][g * 16 + lk * 4] = pk;
        }

        // ---- av from LDS (swizzled v reads), own 32-c chunk ----
        bf16x8 av[2];
#pragma unroll
        for (int ct = 0; ct < 2; ++ct) {
            int cl = w * 32 + ct * 16 + lr;                // local c row
            int ph = lk ^ ((lr >> 1) & 3);
            av[ct] = *(const bf16x8*)&vlds[buf][cl * 32 + ph * 8];
        }

        __syncthreads();   // publishes P[buf]; drains next-tile staging

        // ---- PV: acc[c, j] += v[c, i-tile] * P[i-tile, j] ----
        bf16x8 bp[4];
#pragma unroll
        for (int js = 0; js < 4; ++js)
            bp[js] = *(const bf16x8*)&P[buf][js][lr][lk * 8];
#pragma unroll
        for (int ct = 0; ct < 2; ++ct)
#pragma unroll
            for (int js = 0; js < 4; ++js)
                acc[ct][js] = __builtin_amdgcn_mfma_f32_16x16x32_bf16(av[ct], bp[js], acc[ct][js], 0, 0, 0);
    }

    // ---- epilogue: combine per-lane L partials, normalize, residual ----
    lsum += __shfl_xor(lsum, 16);
    lsum += __shfl_xor(lsum, 32);     // full column sum for column (w, lr)
    if (lane < 16) Ls[w][lr] = lsum;
    __syncthreads();
    float g = gamma[0];
    float linv[4];
#pragma unroll
    for (int js = 0; js < 4; ++js) linv[js] = g / Ls[js][lr];
#pragma unroll
    for (int ct = 0; ct < 2; ++ct)
#pragma unroll
        for (int r = 0; r < 4; ++r) {
            int c = c0 + w * 32 + ct * 16 + lk * 4 + r;
            size_t base = ((size_t)(b * 256 + c)) * 4096 + j0;
#pragma unroll
            for (int js = 0; js < 4; ++js) {
                int j = js * 16 + lr;
                out[base + j] = acc[ct][js][r] * linv[js] + x[base + j];
            }
        }
}

// ---------------------------------------------------------------------------
extern "C" void kernel_launch(void* const* d_in, const int* in_sizes, int n_in,
                              void* d_out, int out_size, void* d_ws, size_t ws_size,
                              hipStream_t stream) {
    const float* x = (const float*)d_in[0];
    const float* Wq = (const float*)d_in[1];
    const float* bq = (const float*)d_in[2];
    const float* Wk = (const float*)d_in[3];
    const float* bk = (const float*)d_in[4];
    const float* Wv = (const float*)d_in[5];
    const float* bv = (const float*)d_in[6];
    const float* gamma = (const float*)d_in[7];

    char* ws = (char*)d_ws;
    u16* Whi = (u16*)ws;                               // 163840 B
    u16* Wlo = (u16*)(ws + 163840);                    // 163840 B
    float* bias = (float*)(ws + 327680);               // 1280 B
    u16* qt = (u16*)(ws + 329216);                     // 4 MB  [8][4096][64]
    u16* kt = (u16*)(ws + 329216 + 4194304);           // 4 MB
    u16* vbf = (u16*)(ws + 329216 + 8388608);          // 16 MB [8][256][4096]
    float* Shf = (float*)(ws + 329216 + 25165824);     // 32 B  [8]

    k_prep<<<320, 256, 0, stream>>>(Wq, bq, Wk, bk, Wv, bv, Whi, Wlo, bias);
    k_proj<<<512, 256, 0, stream>>>(x, Whi, Wlo, bias, qt, kt, vbf);
    k_bound<<<8, 256, 0, stream>>>(qt, kt, Shf);
    k_attn<<<1024, 256, 0, stream>>>(qt, kt, vbf, Shf, x, gamma, (float*)d_out);
}